// Round 1
// baseline (1139.458 us; speedup 1.0000x reference)
//
#include <hip/hip_runtime.h>
#include <hip/hip_bf16.h>

// ---------------------------------------------------------------------------
// MaskedGNN: 6-layer GCN, fp32.
//  deg = 1 + indeg(dst); dis = rsqrt(deg); norm_e = dis[src]*dis[dst]
//  gcn(h,W,b) = segsum(h@W [src]*norm, dst) + (h@W)*dis^2 + b
// Restructured (linearity): aggregate FIRST:  z = segsum(h[src]*norm) + h*dis^2
//                           then  h_next = relu(z @ W + b)
//  encoder: aggregate width-3 x;  decoder: matmul-first (width-1 aggregate)
// CSR built on-device per call (histogram + block-scan + scatter).
// ---------------------------------------------------------------------------

#define HW 128  // hidden width

// ---------------- CSR build ----------------
__global__ void k_zero_i32(int* __restrict__ a, int n) {
    int i = blockIdx.x * 256 + threadIdx.x;
    if (i < n) a[i] = 0;
}

__global__ void k_hist(const int* __restrict__ dstA, int* __restrict__ deg, int e) {
    int i = blockIdx.x * 256 + threadIdx.x;
    if (i < e) atomicAdd(&deg[dstA[i]], 1);
}

__global__ void k_dis(const int* __restrict__ deg, float* __restrict__ dis, int n) {
    int i = blockIdx.x * 256 + threadIdx.x;
    if (i < n) dis[i] = rsqrtf(1.0f + (float)deg[i]);
}

// block-wise inclusive scan (Hillis-Steele in LDS)
__global__ void k_scan_a(const int* __restrict__ deg, int* __restrict__ tmp,
                         int* __restrict__ bsum, int n) {
    __shared__ int s[256];
    int t = threadIdx.x;
    int i = blockIdx.x * 256 + t;
    s[t] = (i < n) ? deg[i] : 0;
    __syncthreads();
    for (int off = 1; off < 256; off <<= 1) {
        int v = (t >= off) ? s[t - off] : 0;
        __syncthreads();
        s[t] += v;
        __syncthreads();
    }
    if (i < n) tmp[i] = s[t];
    if (t == 255) bsum[blockIdx.x] = s[255];
}

__global__ void k_scan_b(int* __restrict__ bsum, int nb) {
    __shared__ int s[512];
    int t = threadIdx.x;
    s[t] = (t < nb) ? bsum[t] : 0;
    __syncthreads();
    for (int off = 1; off < 512; off <<= 1) {
        int v = (t >= off) ? s[t - off] : 0;
        __syncthreads();
        s[t] += v;
        __syncthreads();
    }
    if (t < nb) bsum[t] = s[t];
}

__global__ void k_scan_c(const int* __restrict__ tmp, const int* __restrict__ deg,
                         const int* __restrict__ bsum, int* __restrict__ row_start,
                         int* __restrict__ cursor, int n, int etot) {
    int i = blockIdx.x * 256 + threadIdx.x;
    if (i < n) {
        int off = blockIdx.x ? bsum[blockIdx.x - 1] : 0;
        row_start[i] = tmp[i] - deg[i] + off;  // exclusive scan
        cursor[i] = 0;
    }
    if (i == 0) row_start[n] = etot;
}

__global__ void k_scatter(const int* __restrict__ srcA, const int* __restrict__ dstA,
                          const int* __restrict__ row_start, int* __restrict__ cursor,
                          int* __restrict__ csr, int e) {
    int i = blockIdx.x * 256 + threadIdx.x;
    if (i >= e) return;
    int d = dstA[i];
    int p = atomicAdd(&cursor[d], 1);
    csr[row_start[d] + p] = srcA[i];
}

// ---------------- encoder ----------------
// zx[i] = sum_{e: dst=i} dis[src]*dis[i]*x[src] + dis[i]^2 * x[i]   (width 3, pad to 4)
__global__ void k_enc_agg(const float* __restrict__ x, const int* __restrict__ rs,
                          const int* __restrict__ csr, const float* __restrict__ dis,
                          float* __restrict__ zx, int n) {
    int i = blockIdx.x * 256 + threadIdx.x;
    if (i >= n) return;
    float di = dis[i];
    float sc = di * di;
    float a0 = x[i * 3 + 0] * sc;
    float a1 = x[i * 3 + 1] * sc;
    float a2 = x[i * 3 + 2] * sc;
    int e1 = rs[i + 1];
    for (int j = rs[i]; j < e1; ++j) {
        int s = csr[j];
        float w = dis[s] * di;
        a0 += w * x[s * 3 + 0];
        a1 += w * x[s * 3 + 1];
        a2 += w * x[s * 3 + 2];
    }
    zx[i * 4 + 0] = a0;
    zx[i * 4 + 1] = a1;
    zx[i * 4 + 2] = a2;
    zx[i * 4 + 3] = 0.f;
}

// h[i][c] = relu( zx[i][0..2] . We[:,c] + be[c] )
__global__ void k_enc_gemm(const float* __restrict__ zx, const float* __restrict__ We,
                           const float* __restrict__ be, float* __restrict__ H, int n) {
    int t = blockIdx.x * 256 + threadIdx.x;
    int i = t >> 7;
    int c = t & 127;
    if (i >= n) return;
    float4 z = *(const float4*)&zx[i * 4];
    float v = z.x * We[c] + z.y * We[HW + c] + z.z * We[2 * HW + c] + be[c];
    H[i * HW + c] = fmaxf(v, 0.f);
}

// ---------------- width-128 aggregate: one wave per node ----------------
__global__ __launch_bounds__(256) void k_agg128(const float* __restrict__ H,
                                                const int* __restrict__ rs,
                                                const int* __restrict__ csr,
                                                const float* __restrict__ dis,
                                                float* __restrict__ Z, int n) {
    int node = blockIdx.x * 4 + (threadIdx.x >> 6);
    int lane = threadIdx.x & 63;
    if (node >= n) return;
    const float2* H2 = (const float2*)H;
    float di = dis[node];
    float2 hv = H2[node * 64 + lane];
    float sc = di * di;
    float2 acc;
    acc.x = hv.x * sc;
    acc.y = hv.y * sc;
    int e0 = rs[node], e1 = rs[node + 1];
    for (int j = e0; j < e1; ++j) {
        int s = csr[j];
        float w = dis[s] * di;
        float2 v = H2[s * 64 + lane];
        acc.x = fmaf(w, v.x, acc.x);
        acc.y = fmaf(w, v.y, acc.y);
    }
    ((float2*)Z)[node * 64 + lane] = acc;
}

// ---------------- 128x128 fp32 GEMM: Hout = relu(Z @ Wt + b) ----------------
// BM=128 rows/block, full 128 cols, BK=32, 256 threads, 8x8 per-thread tile.
#define BM 128
#define BK 32
__global__ __launch_bounds__(256) void k_gemm128(const float* __restrict__ Z,
                                                 const float* __restrict__ Wt,
                                                 const float* __restrict__ b,
                                                 float* __restrict__ Hout, int n,
                                                 int do_relu) {
    __shared__ float Zs[BM][BK + 1];  // +1 pad: conflict-free column reads
    __shared__ float Ws[BK][HW];
    int tid = threadIdx.x;
    int tx = tid & 15;   // col group: cols tx*8 .. tx*8+7
    int ty = tid >> 4;   // row group: rows ty*8 .. ty*8+7
    int row0 = blockIdx.x * BM;

    float acc[8][8];
#pragma unroll
    for (int i = 0; i < 8; ++i)
#pragma unroll
        for (int j = 0; j < 8; ++j) acc[i][j] = 0.f;

    for (int kc = 0; kc < HW; kc += BK) {
        // stage Z chunk [BM][BK] and W chunk [BK][HW]: 4 float4 each per thread
#pragma unroll
        for (int i = 0; i < 4; ++i) {
            int f = tid + i * 256;  // 0..1023
            int r = f >> 3, q = f & 7;
            int grow = row0 + r;
            float4 v = make_float4(0.f, 0.f, 0.f, 0.f);
            if (grow < n) v = *(const float4*)&Z[grow * HW + kc + q * 4];
            Zs[r][q * 4 + 0] = v.x;
            Zs[r][q * 4 + 1] = v.y;
            Zs[r][q * 4 + 2] = v.z;
            Zs[r][q * 4 + 3] = v.w;
            int kk = f >> 5, c4 = f & 31;
            float4 wv = *(const float4*)&Wt[(kc + kk) * HW + c4 * 4];
            *(float4*)&Ws[kk][c4 * 4] = wv;
        }
        __syncthreads();
#pragma unroll 8
        for (int k = 0; k < BK; ++k) {
            float zr[8];
#pragma unroll
            for (int i = 0; i < 8; ++i) zr[i] = Zs[ty * 8 + i][k];
            float4 w0 = *(const float4*)&Ws[k][tx * 8];
            float4 w1 = *(const float4*)&Ws[k][tx * 8 + 4];
            float wr[8] = {w0.x, w0.y, w0.z, w0.w, w1.x, w1.y, w1.z, w1.w};
#pragma unroll
            for (int i = 0; i < 8; ++i)
#pragma unroll
                for (int j = 0; j < 8; ++j)
                    acc[i][j] = fmaf(zr[i], wr[j], acc[i][j]);
        }
        __syncthreads();
    }

    float br[8];
#pragma unroll
    for (int j = 0; j < 8; ++j) br[j] = b[tx * 8 + j];
#pragma unroll
    for (int i = 0; i < 8; ++i) {
        int grow = row0 + ty * 8 + i;
        if (grow < n) {
            float o[8];
#pragma unroll
            for (int j = 0; j < 8; ++j) {
                float v = acc[i][j] + br[j];
                o[j] = do_relu ? fmaxf(v, 0.f) : v;
            }
            *(float4*)&Hout[grow * HW + tx * 8] = make_float4(o[0], o[1], o[2], o[3]);
            *(float4*)&Hout[grow * HW + tx * 8 + 4] = make_float4(o[4], o[5], o[6], o[7]);
        }
    }
}

// ---------------- decoder ----------------
// t[i] = H[i] . Wd   (wave per node, shuffle reduce)
__global__ __launch_bounds__(256) void k_dec_mv(const float* __restrict__ H,
                                                const float* __restrict__ Wd,
                                                float* __restrict__ t, int n) {
    int node = blockIdx.x * 4 + (threadIdx.x >> 6);
    int lane = threadIdx.x & 63;
    if (node >= n) return;
    float2 h = ((const float2*)H)[node * 64 + lane];
    float2 w = ((const float2*)Wd)[lane];
    float s = h.x * w.x + h.y * w.y;
    for (int off = 32; off; off >>= 1) s += __shfl_down(s, off);
    if (lane == 0) t[node] = s;
}

// out[i] = (segsum(t[src]*norm) + t[i]*dis^2 + b) * mask[i]
__global__ void k_dec_out(const float* __restrict__ t, const int* __restrict__ rs,
                          const int* __restrict__ csr, const float* __restrict__ dis,
                          const float* __restrict__ bdec, const float* __restrict__ mask,
                          float* __restrict__ out, int n) {
    int i = blockIdx.x * 256 + threadIdx.x;
    if (i >= n) return;
    float di = dis[i];
    float acc = t[i] * di * di;
    int e1 = rs[i + 1];
    for (int j = rs[i]; j < e1; ++j) {
        int s = csr[j];
        acc = fmaf(dis[s] * di, t[s], acc);
    }
    out[i] = (acc + bdec[0]) * mask[i];
}

// ---------------------------------------------------------------------------
static inline size_t align256(size_t x) { return (x + 255) & ~(size_t)255; }

extern "C" void kernel_launch(void* const* d_in, const int* in_sizes, int n_in,
                              void* d_out, int out_size, void* d_ws, size_t ws_size,
                              hipStream_t stream) {
    const float* x     = (const float*)d_in[0];
    const float* mask  = (const float*)d_in[1];
    const int*   ei    = (const int*)d_in[2];
    const float* W_enc = (const float*)d_in[3];
    const float* b_enc = (const float*)d_in[4];
    const float* W_p   = (const float*)d_in[5];
    const float* b_p   = (const float*)d_in[6];
    const float* W_dec = (const float*)d_in[7];
    const float* b_dec = (const float*)d_in[8];

    const int N = in_sizes[1];      // mask has N elements
    const int E = in_sizes[2] / 2;  // edge_index is [2,E]
    const int* srcA = ei;
    const int* dstA = ei + E;

    // workspace carve-up
    char* p = (char*)d_ws;
    size_t off = 0;
    auto carve = [&](size_t bytes) {
        void* r = p + off;
        off += align256(bytes);
        return r;
    };
    int*   deg       = (int*)carve((size_t)N * 4);
    int*   cursor    = (int*)carve((size_t)N * 4);
    int*   row_start = (int*)carve((size_t)(N + 1) * 4);
    int*   bsum      = (int*)carve(512 * 4);
    int*   csr       = (int*)carve((size_t)E * 4);   // also scan tmp (E >= N)
    float* dis       = (float*)carve((size_t)N * 4);
    float* zx        = (float*)carve((size_t)N * 4 * 4);
    float* tdec      = (float*)carve((size_t)N * 4);
    float* Zbuf      = (float*)carve((size_t)N * HW * 4);
    float* Hbuf      = (float*)carve((size_t)N * HW * 4);

    const int gN   = (N + 255) / 256;
    const int gE   = (E + 255) / 256;
    const int gNd4 = (N + 3) / 4;
    const int gMM  = (N + BM - 1) / BM;

    // ---- CSR build ----
    k_zero_i32<<<gN, 256, 0, stream>>>(deg, N);
    k_hist<<<gE, 256, 0, stream>>>(dstA, deg, E);
    k_dis<<<gN, 256, 0, stream>>>(deg, dis, N);
    k_scan_a<<<gN, 256, 0, stream>>>(deg, csr /*tmp*/, bsum, N);
    k_scan_b<<<1, 512, 0, stream>>>(bsum, gN);
    k_scan_c<<<gN, 256, 0, stream>>>(csr /*tmp*/, deg, bsum, row_start, cursor, N, E);
    k_scatter<<<gE, 256, 0, stream>>>(srcA, dstA, row_start, cursor, csr, E);

    // ---- encoder ----
    k_enc_agg<<<gN, 256, 0, stream>>>(x, row_start, csr, dis, zx, N);
    k_enc_gemm<<<(N * HW + 255) / 256, 256, 0, stream>>>(zx, W_enc, b_enc, Hbuf, N);

    // ---- 4 processor layers ----
    for (int l = 0; l < 4; ++l) {
        k_agg128<<<gNd4, 256, 0, stream>>>(Hbuf, row_start, csr, dis, Zbuf, N);
        k_gemm128<<<gMM, 256, 0, stream>>>(Zbuf, W_p + (size_t)l * HW * HW,
                                           b_p + (size_t)l * HW, Hbuf, N, 1);
    }

    // ---- decoder ----
    k_dec_mv<<<gNd4, 256, 0, stream>>>(Hbuf, W_dec, tdec, N);
    k_dec_out<<<gN, 256, 0, stream>>>(tdec, row_start, csr, dis, b_dec, mask,
                                      (float*)d_out, N);
}

// Round 2
// 916.426 us; speedup vs baseline: 1.2434x; 1.2434x over previous
//
#include <hip/hip_runtime.h>
#include <hip/hip_bf16.h>

// ---------------------------------------------------------------------------
// MaskedGNN: 6-layer GCN, fp32.
//  deg = 1 + indeg(dst); dis = rsqrt(deg); norm_e = dis[src]*dis[dst]
//  gcn(h,W,b) = segsum(h@W [src]*norm, dst) + (h@W)*dis^2 + b
// Restructured (linearity): aggregate FIRST:  z = segsum(h[src]*norm) + h*dis^2
//                           then  h_next = relu(z @ W + b)
//  encoder: aggregate width-3 x;  decoder: matmul-first (width-1 aggregate)
// CSR built on-device per call. Edge records packed as int2{src, f32 weight}.
// Aggregation: wave/node, shfl-broadcast edge chunks, 8-deep unrolled gather.
// ---------------------------------------------------------------------------

#define HW 128  // hidden width

// ---------------- CSR build ----------------
__global__ void k_zero_i32(int* __restrict__ a, int n) {
    int i = blockIdx.x * 256 + threadIdx.x;
    if (i < n) a[i] = 0;
}

__global__ void k_hist(const int* __restrict__ dstA, int* __restrict__ deg, int e) {
    int i = blockIdx.x * 256 + threadIdx.x;
    if (i < e) atomicAdd(&deg[dstA[i]], 1);
}

__global__ void k_dis(const int* __restrict__ deg, float* __restrict__ dis, int n) {
    int i = blockIdx.x * 256 + threadIdx.x;
    if (i < n) dis[i] = rsqrtf(1.0f + (float)deg[i]);
}

// block-wise inclusive scan (Hillis-Steele in LDS)
__global__ void k_scan_a(const int* __restrict__ deg, int* __restrict__ tmp,
                         int* __restrict__ bsum, int n) {
    __shared__ int s[256];
    int t = threadIdx.x;
    int i = blockIdx.x * 256 + t;
    s[t] = (i < n) ? deg[i] : 0;
    __syncthreads();
    for (int off = 1; off < 256; off <<= 1) {
        int v = (t >= off) ? s[t - off] : 0;
        __syncthreads();
        s[t] += v;
        __syncthreads();
    }
    if (i < n) tmp[i] = s[t];
    if (t == 255) bsum[blockIdx.x] = s[255];
}

__global__ void k_scan_b(int* __restrict__ bsum, int nb) {
    __shared__ int s[512];
    int t = threadIdx.x;
    s[t] = (t < nb) ? bsum[t] : 0;
    __syncthreads();
    for (int off = 1; off < 512; off <<= 1) {
        int v = (t >= off) ? s[t - off] : 0;
        __syncthreads();
        s[t] += v;
        __syncthreads();
    }
    if (t < nb) bsum[t] = s[t];
}

__global__ void k_scan_c(const int* __restrict__ tmp, const int* __restrict__ deg,
                         const int* __restrict__ bsum, int* __restrict__ row_start,
                         int* __restrict__ cursor, int n, int etot) {
    int i = blockIdx.x * 256 + threadIdx.x;
    if (i < n) {
        int off = blockIdx.x ? bsum[blockIdx.x - 1] : 0;
        row_start[i] = tmp[i] - deg[i] + off;  // exclusive scan
        cursor[i] = 0;
    }
    if (i == 0) row_start[n] = etot;
}

// edata[j] = { src, bitcast(dis[src]*dis[dst]) }
__global__ void k_scatter(const int* __restrict__ srcA, const int* __restrict__ dstA,
                          const int* __restrict__ row_start, int* __restrict__ cursor,
                          const float* __restrict__ dis, int2* __restrict__ edata,
                          int e) {
    int i = blockIdx.x * 256 + threadIdx.x;
    if (i >= e) return;
    int d = dstA[i];
    int s = srcA[i];
    int p = atomicAdd(&cursor[d], 1);
    edata[row_start[d] + p] = make_int2(s, __float_as_int(dis[s] * dis[d]));
}

// ---------------- encoder ----------------
__global__ void k_enc_agg(const float* __restrict__ x, const int* __restrict__ rs,
                          const int2* __restrict__ edata, const float* __restrict__ dis,
                          float* __restrict__ zx, int n) {
    int i = blockIdx.x * 256 + threadIdx.x;
    if (i >= n) return;
    float di = dis[i];
    float sc = di * di;
    float a0 = x[i * 3 + 0] * sc;
    float a1 = x[i * 3 + 1] * sc;
    float a2 = x[i * 3 + 2] * sc;
    int e1 = rs[i + 1];
    for (int j = rs[i]; j < e1; ++j) {
        int2 e = edata[j];
        float w = __int_as_float(e.y);
        a0 = fmaf(w, x[e.x * 3 + 0], a0);
        a1 = fmaf(w, x[e.x * 3 + 1], a1);
        a2 = fmaf(w, x[e.x * 3 + 2], a2);
    }
    zx[i * 4 + 0] = a0;
    zx[i * 4 + 1] = a1;
    zx[i * 4 + 2] = a2;
    zx[i * 4 + 3] = 0.f;
}

__global__ void k_enc_gemm(const float* __restrict__ zx, const float* __restrict__ We,
                           const float* __restrict__ be, float* __restrict__ H, int n) {
    int t = blockIdx.x * 256 + threadIdx.x;
    int i = t >> 7;
    int c = t & 127;
    if (i >= n) return;
    float4 z = *(const float4*)&zx[i * 4];
    float v = z.x * We[c] + z.y * We[HW + c] + z.z * We[2 * HW + c] + be[c];
    H[i * HW + c] = fmaxf(v, 0.f);
}

// ---------------- width-128 aggregate: one wave per node ----------------
// Lane l pre-loads edge (base+l) coalesced; shfl broadcasts (src, w).
// 8 independent accumulators keep 8 gathers of 512B in flight per wave.
__global__ __launch_bounds__(256) void k_agg128(const float* __restrict__ H,
                                                const int* __restrict__ rs,
                                                const int2* __restrict__ edata,
                                                const float* __restrict__ dis,
                                                float* __restrict__ Z, int n) {
    int node = blockIdx.x * 4 + (threadIdx.x >> 6);
    int lane = threadIdx.x & 63;
    if (node >= n) return;
    const float2* H2 = (const float2*)H;
    float di = dis[node];
    float2 hv = H2[(size_t)node * 64 + lane];
    float sc = di * di;
    float2 a0 = make_float2(hv.x * sc, hv.y * sc);
    float2 a1 = make_float2(0.f, 0.f), a2 = a1, a3 = a1;
    float2 a4 = a1, a5 = a1, a6 = a1, a7 = a1;
    int e0 = rs[node], e1 = rs[node + 1];
    for (int base = e0; base < e1; base += 64) {
        int cnt = e1 - base;
        if (cnt > 64) cnt = 64;
        int myj = base + lane;
        int2 ed = (myj < e1) ? edata[myj] : make_int2(0, 0);
        int sl = ed.x;
        float wl = __int_as_float(ed.y);
        int k = 0;
        for (; k + 8 <= cnt; k += 8) {
            int s0 = __shfl(sl, k + 0), s1 = __shfl(sl, k + 1);
            int s2 = __shfl(sl, k + 2), s3 = __shfl(sl, k + 3);
            int s4 = __shfl(sl, k + 4), s5 = __shfl(sl, k + 5);
            int s6 = __shfl(sl, k + 6), s7 = __shfl(sl, k + 7);
            float w0 = __shfl(wl, k + 0), w1 = __shfl(wl, k + 1);
            float w2 = __shfl(wl, k + 2), w3 = __shfl(wl, k + 3);
            float w4 = __shfl(wl, k + 4), w5 = __shfl(wl, k + 5);
            float w6 = __shfl(wl, k + 6), w7 = __shfl(wl, k + 7);
            float2 v0 = H2[(size_t)s0 * 64 + lane];
            float2 v1 = H2[(size_t)s1 * 64 + lane];
            float2 v2 = H2[(size_t)s2 * 64 + lane];
            float2 v3 = H2[(size_t)s3 * 64 + lane];
            float2 v4 = H2[(size_t)s4 * 64 + lane];
            float2 v5 = H2[(size_t)s5 * 64 + lane];
            float2 v6 = H2[(size_t)s6 * 64 + lane];
            float2 v7 = H2[(size_t)s7 * 64 + lane];
            a0.x = fmaf(w0, v0.x, a0.x); a0.y = fmaf(w0, v0.y, a0.y);
            a1.x = fmaf(w1, v1.x, a1.x); a1.y = fmaf(w1, v1.y, a1.y);
            a2.x = fmaf(w2, v2.x, a2.x); a2.y = fmaf(w2, v2.y, a2.y);
            a3.x = fmaf(w3, v3.x, a3.x); a3.y = fmaf(w3, v3.y, a3.y);
            a4.x = fmaf(w4, v4.x, a4.x); a4.y = fmaf(w4, v4.y, a4.y);
            a5.x = fmaf(w5, v5.x, a5.x); a5.y = fmaf(w5, v5.y, a5.y);
            a6.x = fmaf(w6, v6.x, a6.x); a6.y = fmaf(w6, v6.y, a6.y);
            a7.x = fmaf(w7, v7.x, a7.x); a7.y = fmaf(w7, v7.y, a7.y);
        }
        for (; k < cnt; ++k) {
            int s = __shfl(sl, k);
            float w = __shfl(wl, k);
            float2 v = H2[(size_t)s * 64 + lane];
            a0.x = fmaf(w, v.x, a0.x); a0.y = fmaf(w, v.y, a0.y);
        }
    }
    float2 acc;
    acc.x = ((a0.x + a1.x) + (a2.x + a3.x)) + ((a4.x + a5.x) + (a6.x + a7.x));
    acc.y = ((a0.y + a1.y) + (a2.y + a3.y)) + ((a4.y + a5.y) + (a6.y + a7.y));
    ((float2*)Z)[(size_t)node * 64 + lane] = acc;
}

// ---------------- 128x128 fp32 GEMM: Hout = relu(Z @ Wt + b) ----------------
#define BM 128
#define BK 32
__global__ __launch_bounds__(256) void k_gemm128(const float* __restrict__ Z,
                                                 const float* __restrict__ Wt,
                                                 const float* __restrict__ b,
                                                 float* __restrict__ Hout, int n,
                                                 int do_relu) {
    __shared__ float Zs[BM][BK + 1];
    __shared__ float Ws[BK][HW];
    int tid = threadIdx.x;
    int tx = tid & 15;
    int ty = tid >> 4;
    int row0 = blockIdx.x * BM;

    float acc[8][8];
#pragma unroll
    for (int i = 0; i < 8; ++i)
#pragma unroll
        for (int j = 0; j < 8; ++j) acc[i][j] = 0.f;

    for (int kc = 0; kc < HW; kc += BK) {
#pragma unroll
        for (int i = 0; i < 4; ++i) {
            int f = tid + i * 256;
            int r = f >> 3, q = f & 7;
            int grow = row0 + r;
            float4 v = make_float4(0.f, 0.f, 0.f, 0.f);
            if (grow < n) v = *(const float4*)&Z[grow * HW + kc + q * 4];
            Zs[r][q * 4 + 0] = v.x;
            Zs[r][q * 4 + 1] = v.y;
            Zs[r][q * 4 + 2] = v.z;
            Zs[r][q * 4 + 3] = v.w;
            int kk = f >> 5, c4 = f & 31;
            float4 wv = *(const float4*)&Wt[(kc + kk) * HW + c4 * 4];
            *(float4*)&Ws[kk][c4 * 4] = wv;
        }
        __syncthreads();
#pragma unroll 8
        for (int k = 0; k < BK; ++k) {
            float zr[8];
#pragma unroll
            for (int i = 0; i < 8; ++i) zr[i] = Zs[ty * 8 + i][k];
            float4 w0 = *(const float4*)&Ws[k][tx * 8];
            float4 w1 = *(const float4*)&Ws[k][tx * 8 + 4];
            float wr[8] = {w0.x, w0.y, w0.z, w0.w, w1.x, w1.y, w1.z, w1.w};
#pragma unroll
            for (int i = 0; i < 8; ++i)
#pragma unroll
                for (int j = 0; j < 8; ++j)
                    acc[i][j] = fmaf(zr[i], wr[j], acc[i][j]);
        }
        __syncthreads();
    }

    float br[8];
#pragma unroll
    for (int j = 0; j < 8; ++j) br[j] = b[tx * 8 + j];
#pragma unroll
    for (int i = 0; i < 8; ++i) {
        int grow = row0 + ty * 8 + i;
        if (grow < n) {
            float o[8];
#pragma unroll
            for (int j = 0; j < 8; ++j) {
                float v = acc[i][j] + br[j];
                o[j] = do_relu ? fmaxf(v, 0.f) : v;
            }
            *(float4*)&Hout[grow * HW + tx * 8] = make_float4(o[0], o[1], o[2], o[3]);
            *(float4*)&Hout[grow * HW + tx * 8 + 4] = make_float4(o[4], o[5], o[6], o[7]);
        }
    }
}

// ---------------- decoder ----------------
__global__ __launch_bounds__(256) void k_dec_mv(const float* __restrict__ H,
                                                const float* __restrict__ Wd,
                                                float* __restrict__ t, int n) {
    int node = blockIdx.x * 4 + (threadIdx.x >> 6);
    int lane = threadIdx.x & 63;
    if (node >= n) return;
    float2 h = ((const float2*)H)[(size_t)node * 64 + lane];
    float2 w = ((const float2*)Wd)[lane];
    float s = h.x * w.x + h.y * w.y;
    for (int off = 32; off; off >>= 1) s += __shfl_down(s, off);
    if (lane == 0) t[node] = s;
}

__global__ void k_dec_out(const float* __restrict__ t, const int* __restrict__ rs,
                          const int2* __restrict__ edata, const float* __restrict__ dis,
                          const float* __restrict__ bdec, const float* __restrict__ mask,
                          float* __restrict__ out, int n) {
    int i = blockIdx.x * 256 + threadIdx.x;
    if (i >= n) return;
    float di = dis[i];
    float acc = t[i] * di * di;
    int e1 = rs[i + 1];
    for (int j = rs[i]; j < e1; ++j) {
        int2 e = edata[j];
        acc = fmaf(__int_as_float(e.y), t[e.x], acc);
    }
    out[i] = (acc + bdec[0]) * mask[i];
}

// ---------------------------------------------------------------------------
static inline size_t align256(size_t x) { return (x + 255) & ~(size_t)255; }

extern "C" void kernel_launch(void* const* d_in, const int* in_sizes, int n_in,
                              void* d_out, int out_size, void* d_ws, size_t ws_size,
                              hipStream_t stream) {
    const float* x     = (const float*)d_in[0];
    const float* mask  = (const float*)d_in[1];
    const int*   ei    = (const int*)d_in[2];
    const float* W_enc = (const float*)d_in[3];
    const float* b_enc = (const float*)d_in[4];
    const float* W_p   = (const float*)d_in[5];
    const float* b_p   = (const float*)d_in[6];
    const float* W_dec = (const float*)d_in[7];
    const float* b_dec = (const float*)d_in[8];

    const int N = in_sizes[1];
    const int E = in_sizes[2] / 2;
    const int* srcA = ei;
    const int* dstA = ei + E;

    char* p = (char*)d_ws;
    size_t off = 0;
    auto carve = [&](size_t bytes) {
        void* r = p + off;
        off += align256(bytes);
        return r;
    };
    int*   deg       = (int*)carve((size_t)N * 4);
    int*   cursor    = (int*)carve((size_t)N * 4);
    int*   row_start = (int*)carve((size_t)(N + 1) * 4);
    int*   bsum      = (int*)carve(512 * 4);
    int2*  edata     = (int2*)carve((size_t)E * 8);
    float* dis       = (float*)carve((size_t)N * 4);
    float* zx        = (float*)carve((size_t)N * 4 * 4);  // also scan tmp (4N >= N ints)
    float* tdec      = (float*)carve((size_t)N * 4);
    float* Zbuf      = (float*)carve((size_t)N * HW * 4);
    float* Hbuf      = (float*)carve((size_t)N * HW * 4);
    int*   tmp       = (int*)zx;  // scan tmp, used before zx is written

    const int gN   = (N + 255) / 256;
    const int gE   = (E + 255) / 256;
    const int gNd4 = (N + 3) / 4;
    const int gMM  = (N + BM - 1) / BM;

    // ---- CSR build ----
    k_zero_i32<<<gN, 256, 0, stream>>>(deg, N);
    k_hist<<<gE, 256, 0, stream>>>(dstA, deg, E);
    k_dis<<<gN, 256, 0, stream>>>(deg, dis, N);
    k_scan_a<<<gN, 256, 0, stream>>>(deg, tmp, bsum, N);
    k_scan_b<<<1, 512, 0, stream>>>(bsum, gN);
    k_scan_c<<<gN, 256, 0, stream>>>(tmp, deg, bsum, row_start, cursor, N, E);
    k_scatter<<<gE, 256, 0, stream>>>(srcA, dstA, row_start, cursor, dis, edata, E);

    // ---- encoder ----
    k_enc_agg<<<gN, 256, 0, stream>>>(x, row_start, edata, dis, zx, N);
    k_enc_gemm<<<(N * HW + 255) / 256, 256, 0, stream>>>(zx, W_enc, b_enc, Hbuf, N);

    // ---- 4 processor layers ----
    for (int l = 0; l < 4; ++l) {
        k_agg128<<<gNd4, 256, 0, stream>>>(Hbuf, row_start, edata, dis, Zbuf, N);
        k_gemm128<<<gMM, 256, 0, stream>>>(Zbuf, W_p + (size_t)l * HW * HW,
                                           b_p + (size_t)l * HW, Hbuf, N, 1);
    }

    // ---- decoder ----
    k_dec_mv<<<gNd4, 256, 0, stream>>>(Hbuf, W_dec, tdec, N);
    k_dec_out<<<gN, 256, 0, stream>>>(tdec, row_start, edata, dis, b_dec, mask,
                                      (float*)d_out, N);
}